// Round 29
// baseline (1786.576 us; speedup 1.0000x reference)
//
#include <hip/hip_runtime.h>
#include <math.h>

typedef __attribute__((ext_vector_type(4))) float f32x4v;
typedef __attribute__((ext_vector_type(8))) __bf16 bf16x8v;
typedef __attribute__((ext_vector_type(2))) uint u32x2v;
typedef __attribute__((ext_vector_type(4))) uint u32x4v;

#define SCALE 0.17677669529663687f
#define TOK 131072
#define MCHUNK 32768
#define T32 ((long)TOK * 32)          // M32 for full-T blocked matrices
#define C32 ((long)MCHUNK * 32)       // M32 for chunk-blocked matrices

__device__ __forceinline__ ushort f2bf(float v){
  const __bf16 b = (__bf16)v;          // native RNE convert
  return __builtin_bit_cast(ushort, b);
}
__device__ __forceinline__ float bflo(uint u){ return __uint_as_float(u << 16); }
__device__ __forceinline__ float bfhi(uint u){ return __uint_as_float(u & 0xffff0000u); }
__device__ __forceinline__ float bf2f(ushort u){ return __uint_as_float((uint)u << 16); }

// load 8 contiguous f32 -> packed bf16 uint4
__device__ __forceinline__ uint4 ld8f(const float* __restrict__ p){
  const float4 a = *(const float4*)p;
  const float4 b = *(const float4*)(p + 4);
  uint4 r;
  r.x = (uint)f2bf(a.x) | ((uint)f2bf(a.y) << 16);
  r.y = (uint)f2bf(a.z) | ((uint)f2bf(a.w) << 16);
  r.z = (uint)f2bf(b.x) | ((uint)f2bf(b.y) << 16);
  r.w = (uint)f2bf(b.z) | ((uint)f2bf(b.w) << 16);
  return r;
}

// ---------------- weight f32 -> bf16 convert, K-blocked output ----------------
__global__ __launch_bounds__(256) void cvtw_k(const float* __restrict__ src,
    ushort* __restrict__ dst, int K, long m32, int n4){
  const int i = blockIdx.x * 256 + threadIdx.x;
  if (i >= n4) return;
  const int flat = i * 4;
  const int r = flat / K, k = flat % K;
  float4 v = ((const float4*)src)[i];
  ushort4 o = { f2bf(v.x), f2bf(v.y), f2bf(v.z), f2bf(v.w) };
  *(ushort4*)(dst + (long)(k >> 5) * m32 + (long)r * 32 + (k & 31)) = o;
}

// ---- gamma-folded weight convert + c1/c2, K-blocked output. one wave/row ----
__global__ __launch_bounds__(64) void cvtwg_k(const float* __restrict__ src,
    const float* __restrict__ gma, const float* __restrict__ bta,
    ushort* __restrict__ dst, float* __restrict__ c1, float* __restrict__ c2,
    int K, long m32){
  const int n = blockIdx.x, lane = threadIdx.x;
  const float* sp = src + (long)n * K;
  float s1 = 0.f, s2 = 0.f;
  for (int k = lane * 4; k < K; k += 256){
    float4 wv = *(const float4*)(sp + k);
    float4 gv = *(const float4*)(gma + k);
    float4 bv = *(const float4*)(bta + k);
    s1 += wv.x * gv.x + wv.y * gv.y + wv.z * gv.z + wv.w * gv.w;
    s2 += wv.x * bv.x + wv.y * bv.y + wv.z * bv.z + wv.w * bv.w;
    ushort4 o = { f2bf(wv.x * gv.x), f2bf(wv.y * gv.y), f2bf(wv.z * gv.z), f2bf(wv.w * gv.w) };
    *(ushort4*)(dst + (long)(k >> 5) * m32 + (long)n * 32 + (k & 31)) = o;
  }
  #pragma unroll
  for (int o = 1; o < 64; o <<= 1){ s1 += __shfl_xor(s1, o); s2 += __shfl_xor(s2, o); }
  if (lane == 0){ c1[n] = s1; c2[n] = s2; }
}

// ---------------- fold per-row partial (sum,sumsq) -> (mean,rstd), D=2048 ----------------
__global__ __launch_bounds__(256) void statsred_k(const float* __restrict__ pb,
    float* __restrict__ stats){
  const int row = blockIdx.x * 256 + threadIdx.x;
  const float2* p = (const float2*)(pb + (long)row * 64);
  float s = 0.f, q = 0.f;
  #pragma unroll
  for (int i = 0; i < 32; ++i){ const float2 v = p[i]; s += v.x; q += v.y; }
  const float mean = s * (1.f / 2048.f);
  const float var = q * (1.f / 2048.f) - mean * mean;
  stats[row * 2] = mean;
  stats[row * 2 + 1] = rsqrtf(var + 1e-5f);
}

// ---------------- row stats over xr, blocked [8][T][32] ----------------
__global__ __launch_bounds__(256) void stats256b_k(const ushort* __restrict__ xb,
    float* __restrict__ stats){
  const int lane = threadIdx.x & 63, wd = threadIdx.x >> 6;
  const long row = (long)blockIdx.x * 4 + wd;
  uint2 u = *(const uint2*)(xb + (long)(lane >> 3) * T32 + row * 32 + (lane & 7) * 4);
  float a = bflo(u.x), b2 = bfhi(u.x), c = bflo(u.y), d = bfhi(u.y);
  float s = a + b2 + c + d;
  float q = a * a + b2 * b2 + c * c + d * d;
  #pragma unroll
  for (int o = 1; o < 64; o <<= 1){ s += __shfl_xor(s, o); q += __shfl_xor(q, o); }
  if (lane == 0){
    float mean = s * (1.f / 256.f);
    float var = q * (1.f / 256.f) - mean * mean;
    stats[row * 2] = mean;
    stats[row * 2 + 1] = rsqrtf(var + 1e-5f);
  }
}

// ---------------- bf16 MFMA GEMM: K-blocked, reg-staged, dbuf LDS, 3-deep prefetch ----------------
// A: [K/32][Ma][32] (aM32), W: [K/32][N][32] (wM32).
// TRB: transposed mode (A = small weight, W = tokens). bias per-m, leaky,
//      per-token stats partials into ost, transposed blocked store (C^T).
// CCAT (TRB only): W tokens read directly from f32 pcd (pcdp) / img (c1v),
//      converted bf16 in-register during staging (k-tile<8 -> pcd, else img).
template<int ACT, int OUTT, int RES, bool LNEPI, int MINB, bool TRB, bool CCAT>
__global__ __launch_bounds__(256, MINB) void gemm_k(
    const ushort* __restrict__ A, const ushort* __restrict__ W,
    const float* __restrict__ bias,
    float* __restrict__ outf, ushort* __restrict__ outb,
    const ushort* __restrict__ res, const float* __restrict__ pcdp,
    const float* __restrict__ stats, const float* __restrict__ c1v,
    const float* __restrict__ c2v, int N, int K, int gx,
    long aM32, long wM32, long oM32, int mOff, float* __restrict__ ost)
{
  __shared__ ushort SH[17408];   // K-loop uses [0,16384); TRB store uses 128x136
  const int tid = threadIdx.x;
  const int lane = tid & 63, w = tid >> 6;
  const int nwg = gridDim.x;
  const int xcd = blockIdx.x & 7;
  const int idx = blockIdx.x >> 3;
  int mBase, nBase;
  if (TRB){
    const int npx = nwg / (8 * gx);        // n-tiles per XCD
    mBase = (idx % gx) * 128;
    nBase = (xcd * npx + idx / gx) * 128;
  } else {
    const int mPerX = nwg / (8 * gx);
    const int sg = idx / (8 * gx);
    const int u  = idx - sg * (8 * gx);
    mBase = ((xcd * mPerX + sg * 8 + (u & 7))) * 128;
    nBase = (u >> 3) * 128;
  }
  const int fr = lane & 15, grp = lane >> 4;
  const int wr = w >> 1, wc = w & 1;

  f32x4v acc[4][4];
  #pragma unroll
  for (int i = 0; i < 4; ++i)
    #pragma unroll
    for (int j = 0; j < 4; ++j) acc[i][j] = (f32x4v){0.f, 0.f, 0.f, 0.f};

  const long aBase = (long)(mBase + w * 32) * 32 + lane * 8;
  const long wBase = (long)(nBase + w * 32) * 32 + lane * 8;
  // CCAT: f32 token source addressing (token tok0 = nBase + w*32 + (lane>>2))
  const long tokRow = (long)(nBase + w * 32 + (lane >> 2)) * 256 + (lane & 3) * 8;
  ushort* Ad0 = &SH[w * 1024 + lane * 8];
  ushort* Bd0 = &SH[4096 + w * 1024 + lane * 8];
  ushort* Ad1 = &SH[8192 + w * 1024 + lane * 8];
  ushort* Bd1 = &SH[12288 + w * 1024 + lane * 8];

  const int NT = K >> 5;   // even for all shapes (8/16/32/64)

#define WLD0(tt) (CCAT ? ld8f(((tt) < 8 ? pcdp : c1v) + tokRow + ((tt) & 7) * 32) \
                       : *(const uint4*)(W + wBase + (long)(tt) * wM32))
#define WLD1(tt) (CCAT ? ld8f(((tt) < 8 ? pcdp : c1v) + tokRow + 4096 + ((tt) & 7) * 32) \
                       : *(const uint4*)(W + wBase + (long)(tt) * wM32 + 512))

#define MFMASTEP(ao, bo) do { \
    bf16x8v af[4], bv[4]; \
    _Pragma("unroll") \
    for (int i = 0; i < 4; ++i) \
      af[i] = *(const bf16x8v*)&SH[(ao) + (wr * 64 + i * 16 + fr) * 32 + grp * 8]; \
    _Pragma("unroll") \
    for (int j = 0; j < 4; ++j) \
      bv[j] = *(const bf16x8v*)&SH[(bo) + (wc * 64 + j * 16 + fr) * 32 + grp * 8]; \
    _Pragma("unroll") \
    for (int i = 0; i < 4; ++i) \
      _Pragma("unroll") \
      for (int j = 0; j < 4; ++j) \
        acc[i][j] = __builtin_amdgcn_mfma_f32_16x16x32_bf16(af[i], bv[j], acc[i][j], 0, 0, 0); \
  } while (0)

  // prologue: tile0 -> buf0 (via regs); tile1 -> set P; tile2 -> set Q
  {
    uint4 x0 = *(const uint4*)(A + aBase);
    uint4 x1 = *(const uint4*)(A + aBase + 512);
    uint4 y0 = WLD0(0);
    uint4 y1 = WLD1(0);
    *(uint4*)Ad0 = x0; *(uint4*)(Ad0 + 512) = x1;
    *(uint4*)Bd0 = y0; *(uint4*)(Bd0 + 512) = y1;
  }
  uint4 pa0 = *(const uint4*)(A + aBase + aM32);
  uint4 pa1 = *(const uint4*)(A + aBase + aM32 + 512);
  uint4 pb0 = WLD0(1);
  uint4 pb1 = WLD1(1);
  uint4 qa0 = *(const uint4*)(A + aBase + 2 * aM32);
  uint4 qa1 = *(const uint4*)(A + aBase + 2 * aM32 + 512);
  uint4 qb0 = WLD0(2);
  uint4 qb1 = WLD1(2);
  __syncthreads();

  for (int t = 0; t < NT; t += 2){
    MFMASTEP(0, 4096);
    *(uint4*)Ad1 = pa0; *(uint4*)(Ad1 + 512) = pa1;
    *(uint4*)Bd1 = pb0; *(uint4*)(Bd1 + 512) = pb1;
    if (t + 3 < NT){
      const long ao = aBase + (long)(t + 3) * aM32;
      pa0 = *(const uint4*)(A + ao);
      pa1 = *(const uint4*)(A + ao + 512);
      pb0 = WLD0(t + 3);
      pb1 = WLD1(t + 3);
    }
    __syncthreads();
    MFMASTEP(8192, 12288);
    if (t + 2 < NT){
      *(uint4*)Ad0 = qa0; *(uint4*)(Ad0 + 512) = qa1;
      *(uint4*)Bd0 = qb0; *(uint4*)(Bd0 + 512) = qb1;
      if (t + 4 < NT){
        const long ao = aBase + (long)(t + 4) * aM32;
        qa0 = *(const uint4*)(A + ao);
        qa1 = *(const uint4*)(A + ao + 512);
        qb0 = WLD0(t + 4);
        qb1 = WLD1(t + 4);
      }
    }
    __syncthreads();
  }
#undef MFMASTEP
#undef WLD0
#undef WLD1

  if (TRB){
    // ---- transposed epilogue: bias per-m, leaky, per-token stats, C^T store ----
    float bm[16];
    #pragma unroll
    for (int i = 0; i < 4; ++i)
      #pragma unroll
      for (int rr = 0; rr < 4; ++rr)
        bm[i * 4 + rr] = bias[mBase + wr * 64 + i * 16 + grp * 4 + rr];
    float csum[4], csq[4];
    #pragma unroll
    for (int j = 0; j < 4; ++j){ csum[j] = 0.f; csq[j] = 0.f; }
    #pragma unroll
    for (int j = 0; j < 4; ++j){
      #pragma unroll
      for (int i = 0; i < 4; ++i){
        #pragma unroll
        for (int rr = 0; rr < 4; ++rr){
          float v = acc[i][j][rr] + bm[i * 4 + rr];
          v = v > 0.f ? v : 0.01f * v;
          acc[i][j][rr] = v;
          csum[j] += v; csq[j] += v * v;
        }
      }
    }
    const int mT = mBase >> 7;
    #pragma unroll
    for (int j = 0; j < 4; ++j){
      float s = csum[j], q = csq[j];
      s += __shfl_xor(s, 16); q += __shfl_xor(q, 16);
      s += __shfl_xor(s, 32); q += __shfl_xor(q, 32);
      if (lane < 16){
        const long ntok = nBase + wc * 64 + j * 16 + lane;
        ost[ntok * 64 + mT * 4 + wr * 2]     = s;
        ost[ntok * 64 + mT * 4 + wr * 2 + 1] = q;
      }
    }
    // transposed LDS stage: ebT[token][m], stride 136 (16B-aligned rows)
    ushort* eb = &SH[0];
    __syncthreads();
    #pragma unroll
    for (int j = 0; j < 4; ++j){
      const int ncol = wc * 64 + j * 16 + fr;
      #pragma unroll
      for (int i = 0; i < 4; ++i)
        #pragma unroll
        for (int rr = 0; rr < 4; ++rr)
          eb[ncol * 136 + wr * 64 + i * 16 + grp * 4 + rr] = f2bf(acc[i][j][rr]);
    }
    __syncthreads();
    #pragma unroll
    for (int it = 0; it < 8; ++it){
      const int c = it * 256 + tid;            // 2048 chunks of 16B
      const int trow = c >> 4, cg = c & 15;
      const u32x4v val = *(const u32x4v*)&eb[trow * 136 + cg * 8];
      ushort* dst = outb + (long)((mBase >> 5) + (cg >> 2)) * oM32
                  + (long)(nBase + trow) * 32 + (cg & 3) * 8;
      __builtin_nontemporal_store(val, (u32x4v*)dst);
    }
  } else {
  // ---- standard epilogue ----
  float muv[16], rsv[16];
  if (LNEPI){
    #pragma unroll
    for (int i = 0; i < 4; ++i)
      #pragma unroll
      for (int rr = 0; rr < 4; ++rr){
        const int m = mBase + wr * 64 + i * 16 + grp * 4 + rr;
        muv[i * 4 + rr] = stats[m * 2];
        rsv[i * 4 + rr] = stats[m * 2 + 1];
      }
  }
  float rsum[16], rsq[16];
  if (ost){
    #pragma unroll
    for (int t2 = 0; t2 < 16; ++t2){ rsum[t2] = 0.f; rsq[t2] = 0.f; }
  }
  #pragma unroll
  for (int j = 0; j < 4; ++j){
    const int n = nBase + wc * 64 + j * 16 + fr;
    const float bn = bias[n];
    float c1n = 0.f, c2n = 0.f;
    if (LNEPI){ c1n = c1v[n]; c2n = c2v[n]; }
    #pragma unroll
    for (int i = 0; i < 4; ++i){
      #pragma unroll
      for (int rr = 0; rr < 4; ++rr){
        const long m = mBase + wr * 64 + i * 16 + grp * 4 + rr;
        float v = acc[i][j][rr];
        if (LNEPI) v = rsv[i * 4 + rr] * v - muv[i * 4 + rr] * rsv[i * 4 + rr] * c1n + c2n;
        v += bn;
        if (ACT == 1) v = v > 0.f ? v : 0.01f * v;
        if (ACT == 2){
          const float u2 = v * (0.7978845608f + 0.0356774081f * v * v);
          const float t2 = 1.f - 2.f * __builtin_amdgcn_rcpf(__expf(2.f * u2) + 1.f);
          v = 0.5f * v * (1.f + t2);
        }
        if (RES >= 1)
          v += bf2f(res[(long)(n >> 5) * T32 + (mOff + m) * 32 + (n & 31)]);
        if (RES == 2) v += pcdp[(mOff + m) * N + n];
        acc[i][j][rr] = v;
        if (ost){ rsum[i * 4 + rr] += v; rsq[i * 4 + rr] += v * v; }
        if (OUTT == 0) __builtin_nontemporal_store(v, &outf[(mOff + m) * N + n]);
      }
    }
  }
  if (ost){
    const int nT4 = (nBase >> 7) * 4 + wc * 2;
    #pragma unroll
    for (int t2 = 0; t2 < 16; ++t2){
      float s = rsum[t2], q = rsq[t2];
      #pragma unroll
      for (int o = 1; o < 16; o <<= 1){ s += __shfl_xor(s, o); q += __shfl_xor(q, o); }
      if (fr == 0){
        const long m = mBase + wr * 64 + (t2 >> 2) * 16 + grp * 4 + (t2 & 3);
        ost[m * 64 + nT4]     = s;
        ost[m * 64 + nT4 + 1] = q;
      }
    }
  }
  if (OUTT == 1){
    ushort* eb = &SH[0];
    __syncthreads();
    #pragma unroll
    for (int p = 0; p < 2; ++p){
      if (wr == p){
        #pragma unroll
        for (int i = 0; i < 4; ++i)
          #pragma unroll
          for (int rr = 0; rr < 4; ++rr){
            const int rl = i * 16 + grp * 4 + rr;
            #pragma unroll
            for (int j = 0; j < 4; ++j)
              eb[rl * 128 + wc * 64 + j * 16 + fr] = f2bf(acc[i][j][rr]);
          }
      }
      __syncthreads();
      #pragma unroll
      for (int it = 0; it < 4; ++it){
        const int c = it * 256 + tid;           // 1024 chunks of 16B
        const int row = c >> 4, cg = c & 15;
        const u32x4v val = *(const u32x4v*)&eb[row * 128 + cg * 8];
        ushort* dst = outb + (long)(((nBase) >> 5) + (cg >> 2)) * oM32
                    + (long)(mOff + mBase + p * 64 + row) * 32 + (cg & 3) * 8;
        __builtin_nontemporal_store(val, (u32x4v*)dst);
      }
      __syncthreads();
    }
  }
  }
}

// ---------------- MFMA window attention: block = (window, 4-head group), wave = head ----------------
template<int SHIFT>
__global__ __launch_bounds__(256, 2) void attn_k(const ushort* __restrict__ qkv,
    const float* __restrict__ rpb, ushort* __restrict__ outp)
{
  __shared__ ushort Vt[4][2312];   // V^T per head: [d][72-pad]
  __shared__ ushort Pl[4][4616];   // P per head: [q][72-pad]; reused as out stage
  __shared__ float bias_s[4][226];
  __shared__ int code_s[64];
  const int tid = threadIdx.x;
  const int lane = tid & 63, wid = tid >> 6;
  const int hg = blockIdx.x & 1;
  const int bw = blockIdx.x >> 1;
  const int b = bw >> 10, widx = bw & 1023;
  const int wh = widx >> 5, ww = widx & 31;
  const int head = hg * 4 + wid;
  const int fr = lane & 15, grp = lane >> 4;

  for (int i = lane; i < 225; i += 64) bias_s[wid][i] = rpb[i * 8 + head];
  if (SHIFT > 0 && tid < 64){
    const int hh = wh * 8 + (tid >> 3), wwp = ww * 8 + (tid & 7);
    const int rh = (hh < 248) ? 0 : ((hh < 256 - SHIFT) ? 1 : 2);
    const int rw = (wwp < 248) ? 0 : ((wwp < 256 - SHIFT) ? 1 : 2);
    code_s[tid] = rh * 3 + rw;
  }
  #pragma unroll
  for (int it = 0; it < 4; ++it){
    const int c = it * 256 + tid;
    const int row = c >> 4, part = c & 15;
    const int hc = part >> 2, dc = part & 3;
    const int hs = (wh * 8 + (row >> 3) + SHIFT) & 255;
    const int wsm = (ww * 8 + (row & 7) + SHIFT) & 255;
    const long tk = ((long)b * 256 + hs) * 256 + wsm;
    const uint4 vu = *(const uint4*)(qkv + (long)(16 + hg * 4 + hc) * T32 + tk * 32 + dc * 8);
    const ushort* ve = (const ushort*)&vu;
    #pragma unroll
    for (int e = 0; e < 8; ++e)
      Vt[hc][(dc * 8 + e) * 72 + row] = ve[e];
  }
  long tokr[4];
  #pragma unroll
  for (int j = 0; j < 4; ++j){
    const int n = j * 16 + fr;
    const int hs = (wh * 8 + (n >> 3) + SHIFT) & 255;
    const int wsm = (ww * 8 + (n & 7) + SHIFT) & 255;
    tokr[j] = ((long)b * 256 + hs) * 256 + wsm;
  }
  bf16x8v kf[4];
  #pragma unroll
  for (int j = 0; j < 4; ++j)
    kf[j] = *(const bf16x8v*)(qkv + (long)(8 + head) * T32 + tokr[j] * 32 + grp * 8);
  __syncthreads();

  float invs[4][4];
  #pragma unroll
  for (int qi = 0; qi < 4; ++qi){
    const bf16x8v qf = *(const bf16x8v*)(qkv + (long)head * T32 + tokr[qi] * 32 + grp * 8);
    f32x4v sc[4];
    #pragma unroll
    for (int ci = 0; ci < 4; ++ci)
      sc[ci] = __builtin_amdgcn_mfma_f32_16x16x32_bf16(qf, kf[ci],
          (f32x4v){0.f, 0.f, 0.f, 0.f}, 0, 0, 0);
    #pragma unroll
    for (int rr = 0; rr < 4; ++rr){
      const int q = qi * 16 + grp * 4 + rr;
      const int thq = q >> 3, twq = q & 7;
      int codeq = 0;
      if (SHIFT > 0){
        const int hq = wh * 8 + thq, wq = ww * 8 + twq;
        const int rh = (hq < 248) ? 0 : ((hq < 256 - SHIFT) ? 1 : 2);
        const int rw = (wq < 248) ? 0 : ((wq < 256 - SHIFT) ? 1 : 2);
        codeq = rh * 3 + rw;
      }
      const int lbase = (thq + 7 - (fr >> 3)) * 15 + (twq + 7 - (fr & 7));
      float sum = 0.f;
      #pragma unroll
      for (int ci = 0; ci < 4; ++ci){
        float s = sc[ci][rr] * SCALE + bias_s[wid][lbase - ci * 30];
        if (SHIFT > 0 && codeq != code_s[ci * 16 + fr]) s -= 100.f;
        const float p = __expf(s);
        sum += p;
        Pl[wid][q * 72 + ci * 16 + fr] = f2bf(p);
      }
      sum += __shfl_xor(sum, 1);
      sum += __shfl_xor(sum, 2);
      sum += __shfl_xor(sum, 4);
      sum += __shfl_xor(sum, 8);
      invs[qi][rr] = __builtin_amdgcn_rcpf(sum);
    }
  }
  f32x4v o[4][2];
  #pragma unroll
  for (int qi = 0; qi < 4; ++qi)
    #pragma unroll
    for (int di = 0; di < 2; ++di) o[qi][di] = (f32x4v){0.f, 0.f, 0.f, 0.f};
  #pragma unroll
  for (int ks = 0; ks < 2; ++ks){
    bf16x8v pa[4], bvv[2];
    #pragma unroll
    for (int qi = 0; qi < 4; ++qi)
      pa[qi] = *(const bf16x8v*)&Pl[wid][(qi * 16 + fr) * 72 + ks * 32 + grp * 8];
    #pragma unroll
    for (int di = 0; di < 2; ++di)
      bvv[di] = *(const bf16x8v*)&Vt[wid][(di * 16 + fr) * 72 + ks * 32 + grp * 8];
    #pragma unroll
    for (int qi = 0; qi < 4; ++qi)
      #pragma unroll
      for (int di = 0; di < 2; ++di)
        o[qi][di] = __builtin_amdgcn_mfma_f32_16x16x32_bf16(pa[qi], bvv[di], o[qi][di], 0, 0, 0);
  }
  #pragma unroll
  for (int qi = 0; qi < 4; ++qi)
    #pragma unroll
    for (int di = 0; di < 2; ++di)
      #pragma unroll
      for (int rr = 0; rr < 4; ++rr)
        Pl[wid][(qi * 16 + grp * 4 + rr) * 72 + di * 16 + fr] =
            f2bf(o[qi][di][rr] * invs[qi][rr]);
  {
    const int n = lane;
    const int hs = (wh * 8 + (n >> 3) + SHIFT) & 255;
    const int wsm = (ww * 8 + (n & 7) + SHIFT) & 255;
    const long tokL = ((long)b * 256 + hs) * 256 + wsm;
    ushort* ob = outp + (long)head * T32 + tokL * 32;
    #pragma unroll
    for (int c4 = 0; c4 < 4; ++c4)
      *(uint4*)(ob + c4 * 8) = *(const uint4*)&Pl[wid][n * 72 + c4 * 8];
  }
}

extern "C" void kernel_launch(void* const* d_in, const int* in_sizes, int n_in,
                              void* d_out, int out_size, void* d_ws, size_t ws_size,
                              hipStream_t stream){
  const float* pcd    = (const float*)d_in[0];
  const float* img    = (const float*)d_in[1];
  const float* rd_w1  = (const float*)d_in[2];
  const float* rd_b1  = (const float*)d_in[3];
  const float* rd_lng = (const float*)d_in[4];
  const float* rd_lnb = (const float*)d_in[5];
  const float* rd_w2  = (const float*)d_in[6];
  const float* rd_b2  = (const float*)d_in[7];
  const float* n1g    = (const float*)d_in[8];
  const float* n1b    = (const float*)d_in[9];
  const float* qkv_w  = (const float*)d_in[10];
  const float* qkv_b  = (const float*)d_in[11];
  const float* rpb    = (const float*)d_in[12];
  const float* proj_w = (const float*)d_in[13];
  const float* proj_b = (const float*)d_in[14];
  const float* n2g    = (const float*)d_in[15];
  const float* n2b    = (const float*)d_in[16];
  const float* mlp_w1 = (const float*)d_in[17];
  const float* mlp_b1 = (const float*)d_in[18];
  const float* mlp_w2 = (const float*)d_in[19];
  const float* mlp_b2 = (const float*)d_in[20];

  char* ws = (char*)d_ws;
  ushort* w1b    = (ushort*)(ws + 0);                // 2048x512 bf16   2 MB
  ushort* w2g    = (ushort*)(ws + 2097152);          // 256x2048 (γ·w)  1 MB
  ushort* qkvwg  = (ushort*)(ws + 3145728);          // 2x768x256 (γ·w) 0.75 MB
  ushort* projwb = (ushort*)(ws + 3932160);          // 2x256x256       0.25 MB
  ushort* mlp1wg = (ushort*)(ws + 4194304);          // 2x1024x256 (γ·w) 1 MB
  ushort* mlp2wb = (ushort*)(ws + 5242880);          // 2x256x1024      1 MB
  float*  cvec   = (float*)(ws + 6291456);           // 32 KB c1/c2 pool
  float*  w2c1   = cvec,        *w2c2   = cvec + 256;
  float*  qkvc1  = cvec + 512,  *qkvc2  = cvec + 2048;   // 2x768 each
  float*  mlp1c1 = cvec + 3584, *mlp1c2 = cvec + 5632;   // 2x1024 each
  float*  stats  = (float*)(ws + 6324224);           // T x 2 f32  1 MB
  ushort* xr     = (ushort*)(ws + 7372800);          // residual, blocked [8][T][32]  67 MB
  char*   big    = ws + 74481664;                    // 268,435,456 B region
  ushort* X1c    = (ushort*)(big + 134217728);       // blocked [64][32768][32] (134 MB)
  ushort* qkvb   = (ushort*)big;                     // blocked [24][T][32] (201 MB)
  ushort* attno  = (ushort*)(big + 201326592);       // blocked [8][T][32] (67 MB)
  ushort* hidden = (ushort*)big;                     // blocked [32][T][32] (268 MB)
  float* xout = (float*)d_out;                       // final output f32
  float* pstat = (float*)d_out;                      // 8 MB scratch (overwritten by final GEMM)
  // peak ws use = 74,481,664 + 268,435,456 = 342,917,120 B

  // ---- weight preprocessing (blocked) ----
  cvtw_k<<<1024, 256, 0, stream>>>(rd_w1, w1b, 512, 65536, 262144);
  cvtwg_k<<<256, 64, 0, stream>>>(rd_w2, rd_lng, rd_lnb, w2g, w2c1, w2c2, 2048, 8192);
  for (int i = 0; i < 2; ++i){
    cvtw_k<<<64,  256, 0, stream>>>(proj_w + i * 65536, projwb + i * 65536, 256, 8192, 16384);
    cvtw_k<<<256, 256, 0, stream>>>(mlp_w2 + i * 262144, mlp2wb + i * 262144, 1024, 8192, 65536);
    cvtwg_k<<<768, 64, 0, stream>>>(qkv_w + i * 196608, n1g + i * 256, n1b + i * 256,
        qkvwg + i * 196608, qkvc1 + i * 768, qkvc2 + i * 768, 256, 24576);
    cvtwg_k<<<1024, 64, 0, stream>>>(mlp_w1 + i * 262144, n2g + i * 256, n2b + i * 256,
        mlp1wg + i * 262144, mlp1c1 + i * 1024, mlp1c2 + i * 1024, 256, 32768);
  }

  // ---- reduce block, chunked over M (GEMM1 transposed, concat fused into staging) ----
  for (int c = 0; c < 4; ++c){
    const long off = (long)c * MCHUNK;
    gemm_k<1,1,0,false,2,true,true><<<4096, 256, 0, stream>>>(w1b, nullptr,
        rd_b1, nullptr, X1c, nullptr, pcd + off * 256, nullptr, img + off * 256, nullptr,
        32768, 512, 16, 65536, C32, C32, 0, pstat);
    statsred_k<<<128, 256, 0, stream>>>(pstat, stats + off * 2);
    gemm_k<0,1,0,true,2,false,false><<<512, 256, 0, stream>>>(X1c, w2g, rd_b2,
        nullptr, xr, nullptr, nullptr,
        stats + off * 2, w2c1, w2c2,
        256, 2048, 2, C32, 8192, T32, (int)off, nullptr);
  }
  stats256b_k<<<TOK / 4, 256, 0, stream>>>(xr, stats);

  // ---- Swin layers ----
  for (int i = 0; i < 2; ++i){
    gemm_k<0,1,0,true,2,false,false><<<6144, 256, 0, stream>>>(xr, qkvwg + i * 196608,
        qkv_b + i * 768, nullptr, qkvb, nullptr, nullptr, stats,
        qkvc1 + i * 768, qkvc2 + i * 768, 768, 256, 6, T32, 24576, T32, 0, nullptr);
    if (i == 0)
      attn_k<0><<<4096, 256, 0, stream>>>(qkvb, rpb, attno);
    else
      attn_k<4><<<4096, 256, 0, stream>>>(qkvb, rpb + 1800, attno);
    gemm_k<0,1,1,false,2,false,false><<<2048, 256, 0, stream>>>(attno, projwb + i * 65536,
        proj_b + i * 256, nullptr, xr, xr, nullptr, nullptr, nullptr, nullptr,
        256, 256, 2, T32, 8192, T32, 0, nullptr);
    stats256b_k<<<TOK / 4, 256, 0, stream>>>(xr, stats);
    gemm_k<2,1,0,true,2,false,false><<<8192, 256, 0, stream>>>(xr, mlp1wg + i * 262144,
        mlp_b1 + i * 1024, nullptr, hidden, nullptr, nullptr,
        stats, mlp1c1 + i * 1024, mlp1c2 + i * 1024,
        1024, 256, 8, T32, 32768, T32, 0, nullptr);
    if (i == 0){
      gemm_k<0,1,1,false,2,false,false><<<2048, 256, 0, stream>>>(hidden, mlp2wb, mlp_b2,
          nullptr, xr, xr, nullptr, nullptr, nullptr, nullptr,
          256, 1024, 2, T32, 8192, T32, 0, nullptr);
      stats256b_k<<<TOK / 4, 256, 0, stream>>>(xr, stats);
    } else {
      gemm_k<0,0,2,false,2,false,false><<<2048, 256, 0, stream>>>(hidden, mlp2wb + 262144,
          mlp_b2 + 256, xout, nullptr, xr, pcd, nullptr, nullptr, nullptr,
          256, 1024, 2, T32, 8192, T32, 0, nullptr);
    }
  }
}

// Round 30
// 1719.748 us; speedup vs baseline: 1.0389x; 1.0389x over previous
//
#include <hip/hip_runtime.h>
#include <math.h>

typedef __attribute__((ext_vector_type(4))) float f32x4v;
typedef __attribute__((ext_vector_type(8))) __bf16 bf16x8v;
typedef __attribute__((ext_vector_type(2))) uint u32x2v;
typedef __attribute__((ext_vector_type(4))) uint u32x4v;

#define SCALE 0.17677669529663687f
#define TOK 131072
#define MCHUNK 32768
#define T32 ((long)TOK * 32)          // M32 for full-T blocked matrices
#define C32 ((long)MCHUNK * 32)       // M32 for chunk-blocked matrices

__device__ __forceinline__ ushort f2bf(float v){
  const __bf16 b = (__bf16)v;          // native RNE convert
  return __builtin_bit_cast(ushort, b);
}
__device__ __forceinline__ float bflo(uint u){ return __uint_as_float(u << 16); }
__device__ __forceinline__ float bfhi(uint u){ return __uint_as_float(u & 0xffff0000u); }
__device__ __forceinline__ float bf2f(ushort u){ return __uint_as_float((uint)u << 16); }

// ---------------- weight f32 -> bf16 convert, K-blocked output ----------------
__global__ __launch_bounds__(256) void cvtw_k(const float* __restrict__ src,
    ushort* __restrict__ dst, int K, long m32, int n4){
  const int i = blockIdx.x * 256 + threadIdx.x;
  if (i >= n4) return;
  const int flat = i * 4;
  const int r = flat / K, k = flat % K;
  float4 v = ((const float4*)src)[i];
  ushort4 o = { f2bf(v.x), f2bf(v.y), f2bf(v.z), f2bf(v.w) };
  *(ushort4*)(dst + (long)(k >> 5) * m32 + (long)r * 32 + (k & 31)) = o;
}

// ---- gamma-folded weight convert + c1/c2, K-blocked output. one wave/row ----
__global__ __launch_bounds__(64) void cvtwg_k(const float* __restrict__ src,
    const float* __restrict__ gma, const float* __restrict__ bta,
    ushort* __restrict__ dst, float* __restrict__ c1, float* __restrict__ c2,
    int K, long m32){
  const int n = blockIdx.x, lane = threadIdx.x;
  const float* sp = src + (long)n * K;
  float s1 = 0.f, s2 = 0.f;
  for (int k = lane * 4; k < K; k += 256){
    float4 wv = *(const float4*)(sp + k);
    float4 gv = *(const float4*)(gma + k);
    float4 bv = *(const float4*)(bta + k);
    s1 += wv.x * gv.x + wv.y * gv.y + wv.z * gv.z + wv.w * gv.w;
    s2 += wv.x * bv.x + wv.y * bv.y + wv.z * bv.z + wv.w * bv.w;
    ushort4 o = { f2bf(wv.x * gv.x), f2bf(wv.y * gv.y), f2bf(wv.z * gv.z), f2bf(wv.w * gv.w) };
    *(ushort4*)(dst + (long)(k >> 5) * m32 + (long)n * 32 + (k & 31)) = o;
  }
  #pragma unroll
  for (int o = 1; o < 64; o <<= 1){ s1 += __shfl_xor(s1, o); s2 += __shfl_xor(s2, o); }
  if (lane == 0){ c1[n] = s1; c2[n] = s2; }
}

// ---------------- concat pcd|img -> bf16 A0, chunk-blocked [4][K/32][32768][32] ----------------
__global__ __launch_bounds__(256) void concat_k(const float* __restrict__ pcd,
    const float* __restrict__ img, ushort* __restrict__ A0){
  const long gid = (long)blockIdx.x * 256 + threadIdx.x;  // over T*512/4
  const long t = gid >> 7;
  const int c4 = (int)(gid & 127) * 4;
  const float* src = (c4 < 256) ? (pcd + t * 256 + c4) : (img + t * 256 + (c4 - 256));
  float4 v = *(const float4*)src;
  ushort4 o = { f2bf(v.x), f2bf(v.y), f2bf(v.z), f2bf(v.w) };
  const long chunk = t >> 15, tc = t & 32767;
  ushort* dst = A0 + chunk * 16777216 + (long)(c4 >> 5) * C32 + tc * 32 + (c4 & 31);
  __builtin_nontemporal_store(*(u32x2v*)&o, (u32x2v*)dst);
}

// ---------------- fold per-row partial (sum,sumsq) -> (mean,rstd), D=2048 ----------------
__global__ __launch_bounds__(256) void statsred_k(const float* __restrict__ pb,
    float* __restrict__ stats){
  const int row = blockIdx.x * 256 + threadIdx.x;
  const float2* p = (const float2*)(pb + (long)row * 64);
  float s = 0.f, q = 0.f;
  #pragma unroll
  for (int i = 0; i < 32; ++i){ const float2 v = p[i]; s += v.x; q += v.y; }
  const float mean = s * (1.f / 2048.f);
  const float var = q * (1.f / 2048.f) - mean * mean;
  stats[row * 2] = mean;
  stats[row * 2 + 1] = rsqrtf(var + 1e-5f);
}

// ---------------- row stats over xr, blocked [8][T][32] ----------------
__global__ __launch_bounds__(256) void stats256b_k(const ushort* __restrict__ xb,
    float* __restrict__ stats){
  const int lane = threadIdx.x & 63, wd = threadIdx.x >> 6;
  const long row = (long)blockIdx.x * 4 + wd;
  uint2 u = *(const uint2*)(xb + (long)(lane >> 3) * T32 + row * 32 + (lane & 7) * 4);
  float a = bflo(u.x), b2 = bfhi(u.x), c = bflo(u.y), d = bfhi(u.y);
  float s = a + b2 + c + d;
  float q = a * a + b2 * b2 + c * c + d * d;
  #pragma unroll
  for (int o = 1; o < 64; o <<= 1){ s += __shfl_xor(s, o); q += __shfl_xor(q, o); }
  if (lane == 0){
    float mean = s * (1.f / 256.f);
    float var = q * (1.f / 256.f) - mean * mean;
    stats[row * 2] = mean;
    stats[row * 2 + 1] = rsqrtf(var + 1e-5f);
  }
}

// ---------------- bf16 MFMA GEMM: K-blocked, reg-staged, dbuf LDS, 3-deep prefetch ----------------
// A: [K/32][Ma][32] (aM32), W: [K/32][N][32] (wM32).
// TRB: transposed mode (A = small weight, W = tokens). bias per-m, leaky,
//      per-token stats partials into ost, transposed blocked store (C^T).
template<int ACT, int OUTT, int RES, bool LNEPI, int MINB, bool TRB>
__global__ __launch_bounds__(256, MINB) void gemm_k(
    const ushort* __restrict__ A, const ushort* __restrict__ W,
    const float* __restrict__ bias,
    float* __restrict__ outf, ushort* __restrict__ outb,
    const ushort* __restrict__ res, const float* __restrict__ pcdp,
    const float* __restrict__ stats, const float* __restrict__ c1v,
    const float* __restrict__ c2v, int N, int K, int gx,
    long aM32, long wM32, long oM32, int mOff, float* __restrict__ ost)
{
  __shared__ ushort SH[17408];   // K-loop uses [0,16384); TRB store uses 128x136
  const int tid = threadIdx.x;
  const int lane = tid & 63, w = tid >> 6;
  const int nwg = gridDim.x;
  const int xcd = blockIdx.x & 7;
  const int idx = blockIdx.x >> 3;
  int mBase, nBase;
  if (TRB){
    const int npx = nwg / (8 * gx);        // n-tiles per XCD
    mBase = (idx % gx) * 128;
    nBase = (xcd * npx + idx / gx) * 128;
  } else {
    const int mPerX = nwg / (8 * gx);
    const int sg = idx / (8 * gx);
    const int u  = idx - sg * (8 * gx);
    mBase = ((xcd * mPerX + sg * 8 + (u & 7))) * 128;
    nBase = (u >> 3) * 128;
  }
  const int fr = lane & 15, grp = lane >> 4;
  const int wr = w >> 1, wc = w & 1;

  f32x4v acc[4][4];
  #pragma unroll
  for (int i = 0; i < 4; ++i)
    #pragma unroll
    for (int j = 0; j < 4; ++j) acc[i][j] = (f32x4v){0.f, 0.f, 0.f, 0.f};

  const long aBase = (long)(mBase + w * 32) * 32 + lane * 8;
  const long wBase = (long)(nBase + w * 32) * 32 + lane * 8;
  ushort* Ad0 = &SH[w * 1024 + lane * 8];
  ushort* Bd0 = &SH[4096 + w * 1024 + lane * 8];
  ushort* Ad1 = &SH[8192 + w * 1024 + lane * 8];
  ushort* Bd1 = &SH[12288 + w * 1024 + lane * 8];

  const int NT = K >> 5;   // even for all shapes (8/16/32/64)

#define MFMASTEP(ao, bo) do { \
    bf16x8v af[4], bv[4]; \
    _Pragma("unroll") \
    for (int i = 0; i < 4; ++i) \
      af[i] = *(const bf16x8v*)&SH[(ao) + (wr * 64 + i * 16 + fr) * 32 + grp * 8]; \
    _Pragma("unroll") \
    for (int j = 0; j < 4; ++j) \
      bv[j] = *(const bf16x8v*)&SH[(bo) + (wc * 64 + j * 16 + fr) * 32 + grp * 8]; \
    _Pragma("unroll") \
    for (int i = 0; i < 4; ++i) \
      _Pragma("unroll") \
      for (int j = 0; j < 4; ++j) \
        acc[i][j] = __builtin_amdgcn_mfma_f32_16x16x32_bf16(af[i], bv[j], acc[i][j], 0, 0, 0); \
  } while (0)

  // prologue: tile0 -> buf0 (via regs); tile1 -> set P; tile2 -> set Q
  {
    uint4 x0 = *(const uint4*)(A + aBase);
    uint4 x1 = *(const uint4*)(A + aBase + 512);
    uint4 y0 = *(const uint4*)(W + wBase);
    uint4 y1 = *(const uint4*)(W + wBase + 512);
    *(uint4*)Ad0 = x0; *(uint4*)(Ad0 + 512) = x1;
    *(uint4*)Bd0 = y0; *(uint4*)(Bd0 + 512) = y1;
  }
  uint4 pa0 = *(const uint4*)(A + aBase + aM32);
  uint4 pa1 = *(const uint4*)(A + aBase + aM32 + 512);
  uint4 pb0 = *(const uint4*)(W + wBase + wM32);
  uint4 pb1 = *(const uint4*)(W + wBase + wM32 + 512);
  uint4 qa0 = *(const uint4*)(A + aBase + 2 * aM32);
  uint4 qa1 = *(const uint4*)(A + aBase + 2 * aM32 + 512);
  uint4 qb0 = *(const uint4*)(W + wBase + 2 * wM32);
  uint4 qb1 = *(const uint4*)(W + wBase + 2 * wM32 + 512);
  __syncthreads();

  for (int t = 0; t < NT; t += 2){
    MFMASTEP(0, 4096);
    *(uint4*)Ad1 = pa0; *(uint4*)(Ad1 + 512) = pa1;
    *(uint4*)Bd1 = pb0; *(uint4*)(Bd1 + 512) = pb1;
    if (t + 3 < NT){
      const long ao = aBase + (long)(t + 3) * aM32;
      const long wo = wBase + (long)(t + 3) * wM32;
      pa0 = *(const uint4*)(A + ao);
      pa1 = *(const uint4*)(A + ao + 512);
      pb0 = *(const uint4*)(W + wo);
      pb1 = *(const uint4*)(W + wo + 512);
    }
    __syncthreads();
    MFMASTEP(8192, 12288);
    if (t + 2 < NT){
      *(uint4*)Ad0 = qa0; *(uint4*)(Ad0 + 512) = qa1;
      *(uint4*)Bd0 = qb0; *(uint4*)(Bd0 + 512) = qb1;
      if (t + 4 < NT){
        const long ao = aBase + (long)(t + 4) * aM32;
        const long wo = wBase + (long)(t + 4) * wM32;
        qa0 = *(const uint4*)(A + ao);
        qa1 = *(const uint4*)(A + ao + 512);
        qb0 = *(const uint4*)(W + wo);
        qb1 = *(const uint4*)(W + wo + 512);
      }
    }
    __syncthreads();
  }
#undef MFMASTEP

  if (TRB){
    // ---- transposed epilogue: bias per-m, leaky, per-token stats, C^T store ----
    float bm[16];
    #pragma unroll
    for (int i = 0; i < 4; ++i)
      #pragma unroll
      for (int rr = 0; rr < 4; ++rr)
        bm[i * 4 + rr] = bias[mBase + wr * 64 + i * 16 + grp * 4 + rr];
    float csum[4], csq[4];
    #pragma unroll
    for (int j = 0; j < 4; ++j){ csum[j] = 0.f; csq[j] = 0.f; }
    #pragma unroll
    for (int j = 0; j < 4; ++j){
      #pragma unroll
      for (int i = 0; i < 4; ++i){
        #pragma unroll
        for (int rr = 0; rr < 4; ++rr){
          float v = acc[i][j][rr] + bm[i * 4 + rr];
          v = v > 0.f ? v : 0.01f * v;
          acc[i][j][rr] = v;
          csum[j] += v; csq[j] += v * v;
        }
      }
    }
    const int mT = mBase >> 7;
    #pragma unroll
    for (int j = 0; j < 4; ++j){
      float s = csum[j], q = csq[j];
      s += __shfl_xor(s, 16); q += __shfl_xor(q, 16);
      s += __shfl_xor(s, 32); q += __shfl_xor(q, 32);
      if (lane < 16){
        const long ntok = nBase + wc * 64 + j * 16 + lane;
        ost[ntok * 64 + mT * 4 + wr * 2]     = s;
        ost[ntok * 64 + mT * 4 + wr * 2 + 1] = q;
      }
    }
    // transposed LDS stage: ebT[token][m], stride 136 (16B-aligned rows)
    ushort* eb = &SH[0];
    __syncthreads();
    #pragma unroll
    for (int j = 0; j < 4; ++j){
      const int ncol = wc * 64 + j * 16 + fr;
      #pragma unroll
      for (int i = 0; i < 4; ++i)
        #pragma unroll
        for (int rr = 0; rr < 4; ++rr)
          eb[ncol * 136 + wr * 64 + i * 16 + grp * 4 + rr] = f2bf(acc[i][j][rr]);
    }
    __syncthreads();
    #pragma unroll
    for (int it = 0; it < 8; ++it){
      const int c = it * 256 + tid;            // 2048 chunks of 16B
      const int trow = c >> 4, cg = c & 15;
      const u32x4v val = *(const u32x4v*)&eb[trow * 136 + cg * 8];
      ushort* dst = outb + (long)((mBase >> 5) + (cg >> 2)) * oM32
                  + (long)(nBase + trow) * 32 + (cg & 3) * 8;
      __builtin_nontemporal_store(val, (u32x4v*)dst);
    }
  } else {
  // ---- standard epilogue ----
  float muv[16], rsv[16];
  if (LNEPI){
    #pragma unroll
    for (int i = 0; i < 4; ++i)
      #pragma unroll
      for (int rr = 0; rr < 4; ++rr){
        const int m = mBase + wr * 64 + i * 16 + grp * 4 + rr;
        muv[i * 4 + rr] = stats[m * 2];
        rsv[i * 4 + rr] = stats[m * 2 + 1];
      }
  }
  float rsum[16], rsq[16];
  if (ost){
    #pragma unroll
    for (int t2 = 0; t2 < 16; ++t2){ rsum[t2] = 0.f; rsq[t2] = 0.f; }
  }
  #pragma unroll
  for (int j = 0; j < 4; ++j){
    const int n = nBase + wc * 64 + j * 16 + fr;
    const float bn = bias[n];
    float c1n = 0.f, c2n = 0.f;
    if (LNEPI){ c1n = c1v[n]; c2n = c2v[n]; }
    #pragma unroll
    for (int i = 0; i < 4; ++i){
      #pragma unroll
      for (int rr = 0; rr < 4; ++rr){
        const long m = mBase + wr * 64 + i * 16 + grp * 4 + rr;
        float v = acc[i][j][rr];
        if (LNEPI) v = rsv[i * 4 + rr] * v - muv[i * 4 + rr] * rsv[i * 4 + rr] * c1n + c2n;
        v += bn;
        if (ACT == 1) v = v > 0.f ? v : 0.01f * v;
        if (ACT == 2){
          const float u2 = v * (0.7978845608f + 0.0356774081f * v * v);
          const float t2 = 1.f - 2.f * __builtin_amdgcn_rcpf(__expf(2.f * u2) + 1.f);
          v = 0.5f * v * (1.f + t2);
        }
        if (RES >= 1)
          v += bf2f(res[(long)(n >> 5) * T32 + (mOff + m) * 32 + (n & 31)]);
        if (RES == 2) v += pcdp[(mOff + m) * N + n];
        acc[i][j][rr] = v;
        if (ost){ rsum[i * 4 + rr] += v; rsq[i * 4 + rr] += v * v; }
        if (OUTT == 0) __builtin_nontemporal_store(v, &outf[(mOff + m) * N + n]);
      }
    }
  }
  if (ost){
    const int nT4 = (nBase >> 7) * 4 + wc * 2;
    #pragma unroll
    for (int t2 = 0; t2 < 16; ++t2){
      float s = rsum[t2], q = rsq[t2];
      #pragma unroll
      for (int o = 1; o < 16; o <<= 1){ s += __shfl_xor(s, o); q += __shfl_xor(q, o); }
      if (fr == 0){
        const long m = mBase + wr * 64 + (t2 >> 2) * 16 + grp * 4 + (t2 & 3);
        ost[m * 64 + nT4]     = s;
        ost[m * 64 + nT4 + 1] = q;
      }
    }
  }
  if (OUTT == 1){
    ushort* eb = &SH[0];
    __syncthreads();
    #pragma unroll
    for (int p = 0; p < 2; ++p){
      if (wr == p){
        #pragma unroll
        for (int i = 0; i < 4; ++i)
          #pragma unroll
          for (int rr = 0; rr < 4; ++rr){
            const int rl = i * 16 + grp * 4 + rr;
            #pragma unroll
            for (int j = 0; j < 4; ++j)
              eb[rl * 128 + wc * 64 + j * 16 + fr] = f2bf(acc[i][j][rr]);
          }
      }
      __syncthreads();
      #pragma unroll
      for (int it = 0; it < 4; ++it){
        const int c = it * 256 + tid;           // 1024 chunks of 16B
        const int row = c >> 4, cg = c & 15;
        const u32x4v val = *(const u32x4v*)&eb[row * 128 + cg * 8];
        ushort* dst = outb + (long)(((nBase) >> 5) + (cg >> 2)) * oM32
                    + (long)(mOff + mBase + p * 64 + row) * 32 + (cg & 3) * 8;
        __builtin_nontemporal_store(val, (u32x4v*)dst);
      }
      __syncthreads();
    }
  }
  }
}

// ---------------- MFMA window attention: block = (window, 4-head group), wave = head ----------------
template<int SHIFT>
__global__ __launch_bounds__(256, 2) void attn_k(const ushort* __restrict__ qkv,
    const float* __restrict__ rpb, ushort* __restrict__ outp)
{
  __shared__ ushort Vt[4][2312];   // V^T per head: [d][72-pad]
  __shared__ ushort Pl[4][4616];   // P per head: [q][72-pad]; reused as out stage
  __shared__ float bias_s[4][226];
  __shared__ int code_s[64];
  const int tid = threadIdx.x;
  const int lane = tid & 63, wid = tid >> 6;
  const int hg = blockIdx.x & 1;
  const int bw = blockIdx.x >> 1;
  const int b = bw >> 10, widx = bw & 1023;
  const int wh = widx >> 5, ww = widx & 31;
  const int head = hg * 4 + wid;
  const int fr = lane & 15, grp = lane >> 4;

  for (int i = lane; i < 225; i += 64) bias_s[wid][i] = rpb[i * 8 + head];
  if (SHIFT > 0 && tid < 64){
    const int hh = wh * 8 + (tid >> 3), wwp = ww * 8 + (tid & 7);
    const int rh = (hh < 248) ? 0 : ((hh < 256 - SHIFT) ? 1 : 2);
    const int rw = (wwp < 248) ? 0 : ((wwp < 256 - SHIFT) ? 1 : 2);
    code_s[tid] = rh * 3 + rw;
  }
  #pragma unroll
  for (int it = 0; it < 4; ++it){
    const int c = it * 256 + tid;
    const int row = c >> 4, part = c & 15;
    const int hc = part >> 2, dc = part & 3;
    const int hs = (wh * 8 + (row >> 3) + SHIFT) & 255;
    const int wsm = (ww * 8 + (row & 7) + SHIFT) & 255;
    const long tk = ((long)b * 256 + hs) * 256 + wsm;
    const uint4 vu = *(const uint4*)(qkv + (long)(16 + hg * 4 + hc) * T32 + tk * 32 + dc * 8);
    const ushort* ve = (const ushort*)&vu;
    #pragma unroll
    for (int e = 0; e < 8; ++e)
      Vt[hc][(dc * 8 + e) * 72 + row] = ve[e];
  }
  long tokr[4];
  #pragma unroll
  for (int j = 0; j < 4; ++j){
    const int n = j * 16 + fr;
    const int hs = (wh * 8 + (n >> 3) + SHIFT) & 255;
    const int wsm = (ww * 8 + (n & 7) + SHIFT) & 255;
    tokr[j] = ((long)b * 256 + hs) * 256 + wsm;
  }
  bf16x8v kf[4];
  #pragma unroll
  for (int j = 0; j < 4; ++j)
    kf[j] = *(const bf16x8v*)(qkv + (long)(8 + head) * T32 + tokr[j] * 32 + grp * 8);
  __syncthreads();

  float invs[4][4];
  #pragma unroll
  for (int qi = 0; qi < 4; ++qi){
    const bf16x8v qf = *(const bf16x8v*)(qkv + (long)head * T32 + tokr[qi] * 32 + grp * 8);
    f32x4v sc[4];
    #pragma unroll
    for (int ci = 0; ci < 4; ++ci)
      sc[ci] = __builtin_amdgcn_mfma_f32_16x16x32_bf16(qf, kf[ci],
          (f32x4v){0.f, 0.f, 0.f, 0.f}, 0, 0, 0);
    #pragma unroll
    for (int rr = 0; rr < 4; ++rr){
      const int q = qi * 16 + grp * 4 + rr;
      const int thq = q >> 3, twq = q & 7;
      int codeq = 0;
      if (SHIFT > 0){
        const int hq = wh * 8 + thq, wq = ww * 8 + twq;
        const int rh = (hq < 248) ? 0 : ((hq < 256 - SHIFT) ? 1 : 2);
        const int rw = (wq < 248) ? 0 : ((wq < 256 - SHIFT) ? 1 : 2);
        codeq = rh * 3 + rw;
      }
      const int lbase = (thq + 7 - (fr >> 3)) * 15 + (twq + 7 - (fr & 7));
      float sum = 0.f;
      #pragma unroll
      for (int ci = 0; ci < 4; ++ci){
        float s = sc[ci][rr] * SCALE + bias_s[wid][lbase - ci * 30];
        if (SHIFT > 0 && codeq != code_s[ci * 16 + fr]) s -= 100.f;
        const float p = __expf(s);
        sum += p;
        Pl[wid][q * 72 + ci * 16 + fr] = f2bf(p);
      }
      sum += __shfl_xor(sum, 1);
      sum += __shfl_xor(sum, 2);
      sum += __shfl_xor(sum, 4);
      sum += __shfl_xor(sum, 8);
      invs[qi][rr] = __builtin_amdgcn_rcpf(sum);
    }
  }
  f32x4v o[4][2];
  #pragma unroll
  for (int qi = 0; qi < 4; ++qi)
    #pragma unroll
    for (int di = 0; di < 2; ++di) o[qi][di] = (f32x4v){0.f, 0.f, 0.f, 0.f};
  #pragma unroll
  for (int ks = 0; ks < 2; ++ks){
    bf16x8v pa[4], bvv[2];
    #pragma unroll
    for (int qi = 0; qi < 4; ++qi)
      pa[qi] = *(const bf16x8v*)&Pl[wid][(qi * 16 + fr) * 72 + ks * 32 + grp * 8];
    #pragma unroll
    for (int di = 0; di < 2; ++di)
      bvv[di] = *(const bf16x8v*)&Vt[wid][(di * 16 + fr) * 72 + ks * 32 + grp * 8];
    #pragma unroll
    for (int qi = 0; qi < 4; ++qi)
      #pragma unroll
      for (int di = 0; di < 2; ++di)
        o[qi][di] = __builtin_amdgcn_mfma_f32_16x16x32_bf16(pa[qi], bvv[di], o[qi][di], 0, 0, 0);
  }
  #pragma unroll
  for (int qi = 0; qi < 4; ++qi)
    #pragma unroll
    for (int di = 0; di < 2; ++di)
      #pragma unroll
      for (int rr = 0; rr < 4; ++rr)
        Pl[wid][(qi * 16 + grp * 4 + rr) * 72 + di * 16 + fr] =
            f2bf(o[qi][di][rr] * invs[qi][rr]);
  {
    const int n = lane;
    const int hs = (wh * 8 + (n >> 3) + SHIFT) & 255;
    const int wsm = (ww * 8 + (n & 7) + SHIFT) & 255;
    const long tokL = ((long)b * 256 + hs) * 256 + wsm;
    ushort* ob = outp + (long)head * T32 + tokL * 32;
    #pragma unroll
    for (int c4 = 0; c4 < 4; ++c4)
      *(uint4*)(ob + c4 * 8) = *(const uint4*)&Pl[wid][n * 72 + c4 * 8];
  }
}

extern "C" void kernel_launch(void* const* d_in, const int* in_sizes, int n_in,
                              void* d_out, int out_size, void* d_ws, size_t ws_size,
                              hipStream_t stream){
  const float* pcd    = (const float*)d_in[0];
  const float* img    = (const float*)d_in[1];
  const float* rd_w1  = (const float*)d_in[2];
  const float* rd_b1  = (const float*)d_in[3];
  const float* rd_lng = (const float*)d_in[4];
  const float* rd_lnb = (const float*)d_in[5];
  const float* rd_w2  = (const float*)d_in[6];
  const float* rd_b2  = (const float*)d_in[7];
  const float* n1g    = (const float*)d_in[8];
  const float* n1b    = (const float*)d_in[9];
  const float* qkv_w  = (const float*)d_in[10];
  const float* qkv_b  = (const float*)d_in[11];
  const float* rpb    = (const float*)d_in[12];
  const float* proj_w = (const float*)d_in[13];
  const float* proj_b = (const float*)d_in[14];
  const float* n2g    = (const float*)d_in[15];
  const float* n2b    = (const float*)d_in[16];
  const float* mlp_w1 = (const float*)d_in[17];
  const float* mlp_b1 = (const float*)d_in[18];
  const float* mlp_w2 = (const float*)d_in[19];
  const float* mlp_b2 = (const float*)d_in[20];

  char* ws = (char*)d_ws;
  ushort* w1b    = (ushort*)(ws + 0);                // 2048x512 bf16   2 MB
  ushort* w2g    = (ushort*)(ws + 2097152);          // 256x2048 (γ·w)  1 MB
  ushort* qkvwg  = (ushort*)(ws + 3145728);          // 2x768x256 (γ·w) 0.75 MB
  ushort* projwb = (ushort*)(ws + 3932160);          // 2x256x256       0.25 MB
  ushort* mlp1wg = (ushort*)(ws + 4194304);          // 2x1024x256 (γ·w) 1 MB
  ushort* mlp2wb = (ushort*)(ws + 5242880);          // 2x256x1024      1 MB
  float*  cvec   = (float*)(ws + 6291456);           // 32 KB c1/c2 pool
  float*  w2c1   = cvec,        *w2c2   = cvec + 256;
  float*  qkvc1  = cvec + 512,  *qkvc2  = cvec + 2048;   // 2x768 each
  float*  mlp1c1 = cvec + 3584, *mlp1c2 = cvec + 5632;   // 2x1024 each
  float*  stats  = (float*)(ws + 6324224);           // T x 2 f32  1 MB
  ushort* xr     = (ushort*)(ws + 7372800);          // residual, blocked [8][T][32]  67 MB
  char*   big    = ws + 74481664;                    // 268,435,456 B region
  ushort* A0     = (ushort*)big;                     // blocked [4][16][32768][32] (134 MB)
  ushort* X1c    = (ushort*)(big + 134217728);       // blocked [64][32768][32] (134 MB)
  ushort* qkvb   = (ushort*)big;                     // blocked [24][T][32] (201 MB)
  ushort* attno  = (ushort*)(big + 201326592);       // blocked [8][T][32] (67 MB)
  ushort* hidden = (ushort*)big;                     // blocked [32][T][32] (268 MB)
  float* xout = (float*)d_out;                       // final output f32
  float* pstat = (float*)d_out;                      // 8 MB scratch (overwritten by final GEMM)
  // peak ws use = 74,481,664 + 268,435,456 = 342,917,120 B

  // ---- weight preprocessing (blocked) ----
  cvtw_k<<<1024, 256, 0, stream>>>(rd_w1, w1b, 512, 65536, 262144);
  cvtwg_k<<<256, 64, 0, stream>>>(rd_w2, rd_lng, rd_lnb, w2g, w2c1, w2c2, 2048, 8192);
  for (int i = 0; i < 2; ++i){
    cvtw_k<<<64,  256, 0, stream>>>(proj_w + i * 65536, projwb + i * 65536, 256, 8192, 16384);
    cvtw_k<<<256, 256, 0, stream>>>(mlp_w2 + i * 262144, mlp2wb + i * 262144, 1024, 8192, 65536);
    cvtwg_k<<<768, 64, 0, stream>>>(qkv_w + i * 196608, n1g + i * 256, n1b + i * 256,
        qkvwg + i * 196608, qkvc1 + i * 768, qkvc2 + i * 768, 256, 24576);
    cvtwg_k<<<1024, 64, 0, stream>>>(mlp_w1 + i * 262144, n2g + i * 256, n2b + i * 256,
        mlp1wg + i * 262144, mlp1c1 + i * 1024, mlp1c2 + i * 1024, 256, 32768);
  }
  concat_k<<<65536, 256, 0, stream>>>(pcd, img, A0);

  // ---- reduce block, chunked over M (GEMM1 computed transposed: X1^T = W1 @ X^T) ----
  for (int c = 0; c < 4; ++c){
    const long off = (long)c * MCHUNK;
    gemm_k<1,1,0,false,2,true><<<4096, 256, 0, stream>>>(w1b, A0 + (long)c * 16777216,
        rd_b1, nullptr, X1c, nullptr, nullptr, nullptr, nullptr, nullptr,
        32768, 512, 16, 65536, C32, C32, 0, pstat);
    statsred_k<<<128, 256, 0, stream>>>(pstat, stats + off * 2);
    gemm_k<0,1,0,true,2,false><<<512, 256, 0, stream>>>(X1c, w2g, rd_b2,
        nullptr, xr, nullptr, nullptr,
        stats + off * 2, w2c1, w2c2,
        256, 2048, 2, C32, 8192, T32, (int)off, nullptr);
  }
  stats256b_k<<<TOK / 4, 256, 0, stream>>>(xr, stats);

  // ---- Swin layers ----
  for (int i = 0; i < 2; ++i){
    gemm_k<0,1,0,true,2,false><<<6144, 256, 0, stream>>>(xr, qkvwg + i * 196608,
        qkv_b + i * 768, nullptr, qkvb, nullptr, nullptr, stats,
        qkvc1 + i * 768, qkvc2 + i * 768, 768, 256, 6, T32, 24576, T32, 0, nullptr);
    if (i == 0)
      attn_k<0><<<4096, 256, 0, stream>>>(qkvb, rpb, attno);
    else
      attn_k<4><<<4096, 256, 0, stream>>>(qkvb, rpb + 1800, attno);
    gemm_k<0,1,1,false,2,false><<<2048, 256, 0, stream>>>(attno, projwb + i * 65536,
        proj_b + i * 256, nullptr, xr, xr, nullptr, nullptr, nullptr, nullptr,
        256, 256, 2, T32, 8192, T32, 0, nullptr);
    stats256b_k<<<TOK / 4, 256, 0, stream>>>(xr, stats);
    gemm_k<2,1,0,true,2,false><<<8192, 256, 0, stream>>>(xr, mlp1wg + i * 262144,
        mlp_b1 + i * 1024, nullptr, hidden, nullptr, nullptr,
        stats, mlp1c1 + i * 1024, mlp1c2 + i * 1024,
        1024, 256, 8, T32, 32768, T32, 0, nullptr);
    if (i == 0){
      gemm_k<0,1,1,false,2,false><<<2048, 256, 0, stream>>>(hidden, mlp2wb, mlp_b2,
          nullptr, xr, xr, nullptr, nullptr, nullptr, nullptr,
          256, 1024, 2, T32, 8192, T32, 0, nullptr);
      stats256b_k<<<TOK / 4, 256, 0, stream>>>(xr, stats);
    } else {
      gemm_k<0,0,2,false,2,false><<<2048, 256, 0, stream>>>(hidden, mlp2wb + 262144,
          mlp_b2 + 256, xout, nullptr, xr, pcd, nullptr, nullptr, nullptr,
          256, 1024, 2, T32, 8192, T32, 0, nullptr);
    }
  }
}